// Round 5
// baseline (296.226 us; speedup 1.0000x reference)
//
#include <hip/hip_runtime.h>
#include <float.h>

// Sparsemax per row, one WAVE per row, input read EXACTLY ONCE.
// Row (32 floats/lane) is held in VGPRs and pinned with an opaque asm so the
// compiler cannot rematerialize the global loads (R1 failure mode: VGPR=28,
// row re-read every Newton iter; R4 failure mode: L2/L3 re-read misses).
// tau >= max(x)-1 bounds the support (~20 of 8192 for Gaussian): ballot-
// compact candidates, Newton/Michelot on shuffles, output from registers.

constexpr int D       = 8192;
constexpr int THREADS = 256;
constexpr int WPB     = THREADS / 64;   // 4 rows per block
constexpr int NV      = D / (64 * 4);   // 32 f32x4 per lane... = 32? no: 8192/256 = 32 floats = 8 vec4
constexpr int CAP     = 256;            // per-wave candidate capacity

typedef float f32x4 __attribute__((ext_vector_type(4)));

__global__ __launch_bounds__(THREADS, 4)
void sparsemax_kernel(const float* __restrict__ x, float* __restrict__ out,
                      int rows) {
    __shared__ float cands[WPB][CAP];

    const int wave = threadIdx.x >> 6;
    const int lane = threadIdx.x & 63;
    const long long row = (long long)blockIdx.x * WPB + wave;
    if (row >= rows) return;                       // wave-uniform
    const f32x4* __restrict__ xr4 = reinterpret_cast<const f32x4*>(x + row * D);
    f32x4* __restrict__       or4 = reinterpret_cast<f32x4*>(out + row * D);

    // ---- single HBM read: row -> 8 pinned f32x4 (32 VGPRs), max on the fly
    f32x4 t[NV];
    float m = -FLT_MAX;
    #pragma unroll
    for (int i = 0; i < NV; ++i) {
        t[i] = xr4[lane + i * 64];
        m = fmaxf(m, fmaxf(fmaxf(t[i].x, t[i].y), fmaxf(t[i].z, t[i].w)));
    }
    #pragma unroll
    for (int i = 0; i < NV; ++i)
        asm volatile("" : "+v"(t[i]));   // opaque: kills load rematerialization
    #pragma unroll
    for (int off = 1; off < 64; off <<= 1)
        m = fmaxf(m, __shfl_xor(m, off, 64));
    const float thr = m - 1.0f;          // tau >= thr always

    // ---- ballot-compact candidates (> thr) from registers into LDS ----
    int n = 0;
    #pragma unroll
    for (int i = 0; i < NV; ++i) {
        #pragma unroll
        for (int j = 0; j < 4; ++j) {
            float v = t[i][j];
            unsigned long long mk = __ballot(v > thr);
            if (v > thr) {
                int pos = n + __popcll(mk & ((1ull << lane) - 1ull));
                if (pos < CAP) cands[wave][pos] = v;
            }
            n += __popcll(mk);
        }
    }

    // ---- Newton/Michelot, wave-local ----
    float tau = thr;
    float kprev = -1.0f;
    if (n <= CAP) {
        float c0 = (lane       < n) ? cands[wave][lane      ] : -FLT_MAX;
        float c1 = (lane +  64 < n) ? cands[wave][lane +  64] : -FLT_MAX;
        float c2 = (lane + 128 < n) ? cands[wave][lane + 128] : -FLT_MAX;
        float c3 = (lane + 192 < n) ? cands[wave][lane + 192] : -FLT_MAX;
        for (int it = 0; it < 64; ++it) {          // wave-uniform trip count
            float S = 0.f, K = 0.f;
            if (c0 > tau) { S += c0; K += 1.f; }
            if (c1 > tau) { S += c1; K += 1.f; }
            if (c2 > tau) { S += c2; K += 1.f; }
            if (c3 > tau) { S += c3; K += 1.f; }
            #pragma unroll
            for (int off = 1; off < 64; off <<= 1) {
                S += __shfl_xor(S, off, 64);
                K += __shfl_xor(K, off, 64);
            }
            tau = (S - 1.f) / K;                   // K >= 1: max in support
            if (K == kprev) break;                 // support fixed -> exact
            kprev = K;
        }
    } else {
        // Fallback (unreachable for Gaussian): Michelot over the 32 registers.
        for (int it = 0; it < 64; ++it) {
            float S = 0.f, K = 0.f;
            #pragma unroll
            for (int i = 0; i < NV; ++i) {
                #pragma unroll
                for (int j = 0; j < 4; ++j) {
                    float v = t[i][j];
                    if (v > tau) { S += v; K += 1.f; }
                }
            }
            #pragma unroll
            for (int off = 1; off < 64; off <<= 1) {
                S += __shfl_xor(S, off, 64);
                K += __shfl_xor(K, off, 64);
            }
            tau = (S - 1.f) / K;
            if (K == kprev) break;
            kprev = K;
        }
    }

    // ---- output from pinned registers (no re-read), nontemporal stores ----
    #pragma unroll
    for (int i = 0; i < NV; ++i) {
        f32x4 o;
        o.x = fmaxf(t[i].x - tau, 0.f);
        o.y = fmaxf(t[i].y - tau, 0.f);
        o.z = fmaxf(t[i].z - tau, 0.f);
        o.w = fmaxf(t[i].w - tau, 0.f);
        __builtin_nontemporal_store(o, &or4[lane + i * 64]);
    }
}

extern "C" void kernel_launch(void* const* d_in, const int* in_sizes, int n_in,
                              void* d_out, int out_size, void* d_ws, size_t ws_size,
                              hipStream_t stream) {
    const float* x = (const float*)d_in[0];
    float* out = (float*)d_out;
    const int rows = in_sizes[0] / D;              // 4096
    const int blocks = (rows + WPB - 1) / WPB;     // 1024
    sparsemax_kernel<<<blocks, THREADS, 0, stream>>>(x, out, rows);
}